// Round 17
// baseline (404.669 us; speedup 1.0000x reference)
//
#include <hip/hip_runtime.h>

#define NXN 96
#define NNODE (NXN*NXN)
#define NCW 95
#define NTHREADS 1024
#define NWAVES (NTHREADS/64)
#define MAXIT_OUT 300
#define ATOL_E 4e-3       // absolute tail bound on alpha*gamma (err ~0.8*ATOL, budget 6.33e-3)
#define OMEGA 0.6f        // fine-level smoother (lambda_max <= 3)
#define OMEGA_C 0.45f     // Galerkin coarse levels (lambda_max <= 4)

__device__ __forceinline__ void dual_warp_red(double& a, double& b){
  #pragma unroll
  for (int off = 32; off > 0; off >>= 1){
    a += __shfl_down(a, off, 64);
    b += __shfl_down(b, off, 64);
  }
}

__device__ __forceinline__ double sum16_tree(const double* buf){
  double t0 = buf[0]  + buf[1],  t1 = buf[2]  + buf[3];
  double t2 = buf[4]  + buf[5],  t3 = buf[6]  + buf[7];
  double t4 = buf[8]  + buf[9],  t5 = buf[10] + buf[11];
  double t6 = buf[12] + buf[13], t7 = buf[14] + buf[15];
  double u0 = t0 + t1, u1 = t2 + t3, u2 = t4 + t5, u3 = t6 + t7;
  return (u0 + u1) + (u2 + u3);
}

// ---- level helpers ----
template<int N, int NC>
__device__ __forceinline__ float sgf(const float* sig, int ci, int cj){
  return (ci >= 0 && ci < NC && cj >= 0 && cj < NC) ? sig[cj*NC + ci] : 0.f;
}
template<int N>
__device__ __forceinline__ float vf(const float* v, int i, int j){
  return (i >= 0 && i < N && j >= 0 && j < N) ? v[j*N + i] : 0.f;
}
// Galerkin (per-triangle sigma) 7-pt stencil (verified R11: zero row-sum,
// symmetric, reduces to shared-sigma stencil when sA==sB).
template<int N, int NC>
__device__ __forceinline__ float diagG(const float* sA, const float* sB, int i, int j){
  float a = sgf<N,NC>(sA,i,j),   b = sgf<N,NC>(sA,i-1,j), c = sgf<N,NC>(sB,i-1,j);
  float d = sgf<N,NC>(sA,i,j-1), e = sgf<N,NC>(sB,i,j-1), f = sgf<N,NC>(sB,i-1,j-1);
  return a + 0.5f*b + 2.5f*c + 0.5f*d + 0.5f*e + f;
}
template<int N, int NC>
__device__ __forceinline__ float applyG(const float* sA, const float* sB, const float* v, int i, int j){
  float a = sgf<N,NC>(sA,i,j),   b = sgf<N,NC>(sA,i-1,j), c = sgf<N,NC>(sB,i-1,j);
  float d = sgf<N,NC>(sA,i,j-1), e = sgf<N,NC>(sB,i,j-1), f = sgf<N,NC>(sB,i-1,j-1);
  return (a + 0.5f*b + 2.5f*c + 0.5f*d + 0.5f*e + f)*vf<N>(v,i,j)
       + 0.5f*(e - a)*vf<N>(v,i+1,j)
       + 0.5f*(f - b)*vf<N>(v,i-1,j)
       - (0.5f*a + 1.5f*c)*vf<N>(v,i,j+1)
       - (0.5f*d + 1.5f*f)*vf<N>(v,i,j-1)
       - c*vf<N>(v,i-1,j+1)
       - e*vf<N>(v,i+1,j-1);
}
// residual at a single node (0 on BC row i==0 and out-of-range) — plain function, no lambdas
template<int Nf, int NCf>
__device__ __forceinline__ float resG(const float* sAf, const float* sBf,
                                      const float* ff, const float* zf, int i, int j){
  if (i <= 0 || i >= Nf || j < 0 || j >= Nf) return 0.f;
  return ff[j*Nf + i] - applyG<Nf,NCf>(sAf, sBf, zf, i, j);
}
// fused: residual(fine, on-the-fly) + restrict + smooth-from-zero.
// Safe at small levels only (<=576 outputs -> <=1 node/thread).
template<int Nf, int NCf, int Nc>
__device__ void frrs(const float* sAf, const float* sBf, const float* ff, const float* zf,
                     const float* idc, float* fc, float* zc, int tid){
  for (int n = tid; n < Nc*Nc; n += NTHREADS){
    int I = n % Nc, J = n / Nc;
    float v = 0.f;
    if (I != 0){
      int fi = 2*I, fj = 2*J;
      v = resG<Nf,NCf>(sAf,sBf,ff,zf,fi,fj)
        + 0.5f*( resG<Nf,NCf>(sAf,sBf,ff,zf,fi+1,fj) + resG<Nf,NCf>(sAf,sBf,ff,zf,fi-1,fj)
               + resG<Nf,NCf>(sAf,sBf,ff,zf,fi,fj+1) + resG<Nf,NCf>(sAf,sBf,ff,zf,fi,fj-1)
               + resG<Nf,NCf>(sAf,sBf,ff,zf,fi+1,fj-1) + resG<Nf,NCf>(sAf,sBf,ff,zf,fi-1,fj+1) );
    }
    fc[n] = v;
    zc[n] = v * idc[n];
  }
}
// fused restrict + smooth-from-zero from a PRECOMPUTED fine residual (fine level path)
template<int Nf, int Nc>
__device__ void rrs0(const float* dfine, const float* idl, float* fc, float* zc, int tid){
  for (int n = tid; n < Nc*Nc; n += NTHREADS){
    int I = n % Nc, J = n / Nc;
    float v = 0.f;
    if (I != 0){
      int fi = 2*I, fj = 2*J;
      v = vf<Nf>(dfine,fi,fj)
        + 0.5f*( vf<Nf>(dfine,fi+1,fj) + vf<Nf>(dfine,fi-1,fj)
               + vf<Nf>(dfine,fi,fj+1) + vf<Nf>(dfine,fi,fj-1)
               + vf<Nf>(dfine,fi+1,fj-1) + vf<Nf>(dfine,fi-1,fj+1) );
    }
    fc[n] = v;
    zc[n] = v * idl[n];
  }
}
template<int Nf, int Nc>
__device__ void prolong_add(const float* zc, float* zfine, int tid){
  for (int n = tid; n < Nf*Nf; n += NTHREADS){
    int i = n % Nf, j = n / Nf;
    if (i == 0) continue;
    int ie = i & 1, je = j & 1;
    float add;
    if (!ie && !je)      add = vf<Nc>(zc, i>>1, j>>1);
    else if (ie && !je)  add = 0.5f*(vf<Nc>(zc,(i-1)>>1, j>>1) + vf<Nc>(zc,(i+1)>>1, j>>1));
    else if (!ie && je)  add = 0.5f*(vf<Nc>(zc, i>>1, (j-1)>>1) + vf<Nc>(zc, i>>1, (j+1)>>1));
    else                 add = 0.5f*(vf<Nc>(zc,(i+1)>>1,(j-1)>>1) + vf<Nc>(zc,(i-1)>>1,(j+1)>>1));
    zfine[n] += add;
  }
}
// post-smooth, double-buffered; idl = omega/diag (0 on BC rows)
template<int N, int NC>
__device__ void post_smooth_db(const float* sA, const float* sB, const float* idl, const float* f,
                               const float* zin, float* zout, int tid){
  for (int n = tid; n < N*N; n += NTHREADS){
    int i = n % N, j = n / N;
    zout[n] = zin[n] + (f[n] - applyG<N,NC>(sA,sB,zin,i,j)) * idl[n];
  }
}

__global__ __launch_bounds__(NTHREADS, 1)
void fem_mgcg_kernel(const float* __restrict__ mask, float* __restrict__ out){
  __shared__ float bufA[NNODE];
  __shared__ float bufB[NNODE];
  __shared__ float z1[48*48], f1[48*48], z1b[48*48];
  __shared__ float z2[24*24], f2[24*24], z2b[24*24];
  __shared__ float z3[12*12], f3[12*12], z3b[12*12];
  __shared__ float f4[6*6], z4[6*6], r4[6*6], d4a[6*6], d4b[6*6], zc4[6*6];
  __shared__ float sc1A[47*47], sc1B[47*47];
  __shared__ float sc2A[23*23], sc2B[23*23];
  __shared__ float sc3A[11*11], sc3B[11*11];
  __shared__ float sc4A[5*5],   sc4B[5*5];
  __shared__ float id1[48*48], id2[24*24], id3[12*12], id4[6*6];
  __shared__ double pA[NWAVES], pB[NWAVES];

  const int tid = threadIdx.x, lane = tid & 63, wid = tid >> 6;
  const int bx = tid & 31, by = tid >> 5;
  const int i0 = 3*bx, j0 = 3*by;

  // ---- setup: fine sigma window in registers ----
  float S[4][4];
  #pragma unroll
  for (int a = 0; a < 4; a++)
    #pragma unroll
    for (int b = 0; b < 4; b++){
      int ci = i0-1+a, cj = j0-1+b;
      float m = 0.f;
      if (ci >= 0 && ci < NCW && cj >= 0 && cj < NCW)
        m = 0.001f + 0.999f * mask[cj*NCW + ci];
      S[a][b] = m;
    }
  float invd[3][3];
  #pragma unroll
  for (int di = 0; di < 3; di++)
    #pragma unroll
    for (int dj = 0; dj < 3; dj++){
      float cD = S[di+1][dj+1] + 3.f*S[di][dj+1] + S[di+1][dj] + S[di][dj];
      bool isbc = (i0+di == 0) || (i0+di == NXN-1);
      invd[di][dj] = isbc ? 0.f : 1.f/cD;
    }

  // ---- setup: Galerkin per-triangle sigma hierarchies ----
  for (int n = tid; n < 47*47; n += NTHREADS){
    int CI = n % 47, CJ = n / 47;
    float s00 = 0.001f + 0.999f * mask[(2*CJ)*NCW + (2*CI)];
    float s10 = 0.001f + 0.999f * mask[(2*CJ)*NCW + (2*CI+1)];
    float s01 = 0.001f + 0.999f * mask[(2*CJ+1)*NCW + (2*CI)];
    float s11 = 0.001f + 0.999f * mask[(2*CJ+1)*NCW + (2*CI+1)];
    sc1A[n] = 0.25f*(2.f*s00 + s10 + s01);
    sc1B[n] = 0.25f*(2.f*s11 + s10 + s01);
  }
  __syncthreads();
  for (int n = tid; n < 23*23; n += NTHREADS){
    int CI = n % 23, CJ = n / 23;
    int b00 = (2*CJ)*47 + 2*CI, b10 = b00+1, b01 = b00+47, b11 = b01+1;
    sc2A[n] = 0.25f*(sc1A[b00] + sc1B[b00] + sc1A[b10] + sc1A[b01]);
    sc2B[n] = 0.25f*(sc1A[b11] + sc1B[b11] + sc1B[b10] + sc1B[b01]);
  }
  for (int n = tid; n < 48*48; n += NTHREADS){
    int i = n % 48, j = n / 48;
    id1[n] = (i == 0) ? 0.f : OMEGA_C / diagG<48,47>(sc1A, sc1B, i, j);
  }
  __syncthreads();
  for (int n = tid; n < 11*11; n += NTHREADS){
    int CI = n % 11, CJ = n / 11;
    int b00 = (2*CJ)*23 + 2*CI, b10 = b00+1, b01 = b00+23, b11 = b01+1;
    sc3A[n] = 0.25f*(sc2A[b00] + sc2B[b00] + sc2A[b10] + sc2A[b01]);
    sc3B[n] = 0.25f*(sc2A[b11] + sc2B[b11] + sc2B[b10] + sc2B[b01]);
  }
  for (int n = tid; n < 24*24; n += NTHREADS){
    int i = n % 24, j = n / 24;
    id2[n] = (i == 0) ? 0.f : OMEGA_C / diagG<24,23>(sc2A, sc2B, i, j);
  }
  __syncthreads();
  for (int n = tid; n < 5*5; n += NTHREADS){
    int CI = n % 5, CJ = n / 5;
    int b00 = (2*CJ)*11 + 2*CI, b10 = b00+1, b01 = b00+11, b11 = b01+1;
    sc4A[n] = 0.25f*(sc3A[b00] + sc3B[b00] + sc3A[b10] + sc3A[b01]);
    sc4B[n] = 0.25f*(sc3A[b11] + sc3B[b11] + sc3B[b10] + sc3B[b01]);
  }
  for (int n = tid; n < 12*12; n += NTHREADS){
    int i = n % 12, j = n / 12;
    id3[n] = (i == 0) ? 0.f : OMEGA_C / diagG<12,11>(sc3A, sc3B, i, j);
  }
  __syncthreads();
  for (int n = tid; n < 36; n += NTHREADS){
    int i = n % 6, j = n / 6;
    id4[n] = (i == 0) ? 0.f : 1.f / diagG<6,5>(sc4A, sc4B, i, j);   // plain 1/diag
  }
  __syncthreads();

  #define STENCIL(Wm, di, dj, dst)                                          \
    {                                                                        \
      int i_ = i0+(di);                                                      \
      bool isbc_ = (i_ == 0) || (i_ == NXN-1);                               \
      float s00 = S[(di)+1][(dj)+1], sW = S[(di)][(dj)+1];                   \
      float sS  = S[(di)+1][(dj)],   sWS = S[(di)][(dj)];                    \
      float v_ = (s00 + 3.f*sW + sS + sWS)*Wm[(di)+1][(dj)+1]                \
               + 0.5f*(sS - s00)*Wm[(di)+2][(dj)+1]                          \
               + 0.5f*(sWS - sW)*Wm[(di)][(dj)+1]                            \
               - 0.5f*(s00 + 3.f*sW)*Wm[(di)+1][(dj)+2]                      \
               - 0.5f*(sS + 3.f*sWS)*Wm[(di)+1][(dj)]                        \
               - sW*Wm[(di)][(dj)+2]                                         \
               - sS*Wm[(di)+2][(dj)];                                        \
      dst = isbc_ ? 0.f : v_;                                                \
    }

  #define GATHER5x5(Wm, own, buf)                                           \
    _Pragma("unroll")                                                        \
    for (int a = 0; a < 5; a++)                                              \
      _Pragma("unroll")                                                      \
      for (int b = 0; b < 5; b++){                                           \
        if (a >= 1 && a <= 3 && b >= 1 && b <= 3){ Wm[a][b] = own[a-1][b-1]; continue; } \
        int gi = i0-1+a, gj = j0-1+b;                                        \
        Wm[a][b] = (gi >= 0 && gi < NXN && gj >= 0 && gj < NXN) ? buf[gj*NXN + gi] : 0.f; \
      }

  // Chebyshev(4) bottom-solve on [0.08, 4.0] (Galerkin Gershgorin: lmax<=4)
  const float CH_TH = (4.0f + 0.08f) * 0.5f;
  const float CH_DE = (4.0f - 0.08f) * 0.5f;
  const float CH_SG = CH_TH / CH_DE;
  const float RHO0 = 1.f/CH_SG;
  const float RHO1 = 1.f/(2.f*CH_SG - RHO0);
  const float RHO2 = 1.f/(2.f*CH_SG - RHO1);
  const float RHO3 = 1.f/(2.f*CH_SG - RHO2);
  const float A1 = RHO1*RHO0, B1 = 2.f*RHO1/CH_DE;
  const float A2 = RHO2*RHO1, B2 = 2.f*RHO2/CH_DE;
  const float A3 = RHO3*RHO2, B3 = 2.f*RHO3/CH_DE;

  // ---- warm start u0lin = 1 - i/95 ; r0 = -(A u0lin) on free rows ----
  float x[3][3], r[3][3], z0[3][3], w[3][3], p[3][3], s[3][3];
  #pragma unroll
  for (int di = 0; di < 3; di++)
    #pragma unroll
    for (int dj = 0; dj < 3; dj++){
      x[di][dj] = 0.f; p[di][dj] = 0.f; s[di][dj] = 0.f;
      int i = i0+di;
      float s00 = S[di+1][dj+1], sW = S[di][dj+1], sS = S[di+1][dj], sWS = S[di][dj];
      float uc = 1.f - (float)i     * (1.f/95.f);
      float uE = 1.f - (float)(i+1) * (1.f/95.f);
      float uW = 1.f - (float)(i-1) * (1.f/95.f);
      float v = (s00 + 3.f*sW + sS + sWS)*uc
              + 0.5f*(sS - s00)*uE + 0.5f*(sWS - sW)*uW
              - 0.5f*(s00 + 3.f*sW)*uc - 0.5f*(sS + 3.f*sWS)*uc
              - sW*uW - sS*uE;
      bool isbc = (i == 0) || (i == NXN-1);
      r[di][dj] = isbc ? 0.f : -v;
    }

  double gamma_old = 1.0, alpha_old = 1.0, gamma0 = 0.0;

  // ======== outer PCG (Chronopoulos-Gear) with Galerkin MG V(1,1) ====
  for (int it = 0; it < MAXIT_OUT; ++it){
    // P0: L0 pre-smooth (from zero) + publish to bufA
    #pragma unroll
    for (int di = 0; di < 3; di++)
      #pragma unroll
      for (int dj = 0; dj < 3; dj++){
        float zv = OMEGA * invd[di][dj] * r[di][dj];
        z0[di][dj] = zv;
        bufA[(j0+dj)*NXN + (i0+di)] = zv;
      }
    __syncthreads();
    // P1: fine residual -> bufB
    {
      float Wm[5][5];
      GATHER5x5(Wm, z0, bufA);
      #pragma unroll
      for (int di = 0; di < 3; di++)
        #pragma unroll
        for (int dj = 0; dj < 3; dj++){
          float av; STENCIL(Wm, di, dj, av);
          int i = i0+di;
          bool isbc = (i == 0) || (i == NXN-1);
          bufB[(j0+dj)*NXN + i] = isbc ? 0.f : (r[di][dj] - av);
        }
    }
    __syncthreads();
    // descent: fine restrict, then fused residual+restrict at small levels
    rrs0<96,48>(bufB, id1, f1, z1, tid);                              __syncthreads();
    frrs<48,47,24>(sc1A, sc1B, f1, z1, id2, f2, z2, tid);             __syncthreads();
    frrs<24,23,12>(sc2A, sc2B, f2, z2, id3, f3, z3, tid);             __syncthreads();
    // bottom: fused residual(12)+restrict -> f4, Chebyshev d0
    for (int n = tid; n < 36; n += NTHREADS){
      int I = n % 6, J = n / 6;
      float v = 0.f;
      if (I != 0){
        int fi = 2*I, fj = 2*J;
        v = resG<12,11>(sc3A,sc3B,f3,z3,fi,fj)
          + 0.5f*( resG<12,11>(sc3A,sc3B,f3,z3,fi+1,fj) + resG<12,11>(sc3A,sc3B,f3,z3,fi-1,fj)
                 + resG<12,11>(sc3A,sc3B,f3,z3,fi,fj+1) + resG<12,11>(sc3A,sc3B,f3,z3,fi,fj-1)
                 + resG<12,11>(sc3A,sc3B,f3,z3,fi+1,fj-1) + resG<12,11>(sc3A,sc3B,f3,z3,fi-1,fj+1) );
      }
      f4[n] = v;
      float d0 = (1.f/CH_TH) * v * id4[n];
      d4a[n] = d0; z4[n] = d0;
    }
    __syncthreads();
    // cheb k=1
    for (int n = tid; n < 36; n += NTHREADS){
      int I = n % 6, J = n / 6;
      if (I == 0){ r4[n] = 0.f; d4b[n] = 0.f; continue; }
      float rn = f4[n] - applyG<6,5>(sc4A, sc4B, d4a, I, J);
      r4[n] = rn;
      float dn = A1*d4a[n] + B1*(rn * id4[n]);
      d4b[n] = dn; z4[n] += dn;
    }
    __syncthreads();
    // cheb k=2
    for (int n = tid; n < 36; n += NTHREADS){
      int I = n % 6, J = n / 6;
      if (I == 0){ d4a[n] = 0.f; continue; }
      float rn = r4[n] - applyG<6,5>(sc4A, sc4B, d4b, I, J);
      r4[n] = rn;
      float dn = A2*d4b[n] + B2*(rn * id4[n]);
      d4a[n] = dn; z4[n] += dn;
    }
    __syncthreads();
    // cheb k=3 (final) -> zc4
    for (int n = tid; n < 36; n += NTHREADS){
      int I = n % 6, J = n / 6;
      if (I == 0){ zc4[n] = 0.f; continue; }
      float rn = r4[n] - applyG<6,5>(sc4A, sc4B, d4a, I, J);
      float dn = A3*d4a[n] + B3*(rn * id4[n]);
      zc4[n] = z4[n] + dn;
    }
    __syncthreads();
    // ascent
    prolong_add<12,6>(zc4, z3, tid);                                 __syncthreads();
    post_smooth_db<12,11>(sc3A, sc3B, id3, f3, z3, z3b, tid);        __syncthreads();
    prolong_add<24,12>(z3b, z2, tid);                                __syncthreads();
    post_smooth_db<24,23>(sc2A, sc2B, id2, f2, z2, z2b, tid);        __syncthreads();
    prolong_add<48,24>(z2b, z1, tid);                                __syncthreads();
    post_smooth_db<48,47>(sc1A, sc1B, id1, f1, z1, z1b, tid);        __syncthreads();
    // T1: L0 prolong from z1b into z0 regs + publish bufA
    #pragma unroll
    for (int di = 0; di < 3; di++)
      #pragma unroll
      for (int dj = 0; dj < 3; dj++){
        int i = i0+di, j = j0+dj;
        if (i != 0 && i != NXN-1){
          int ie = i & 1, je = j & 1;
          float add;
          if (!ie && !je)      add = vf<48>(z1b, i>>1, j>>1);
          else if (ie && !je)  add = 0.5f*(vf<48>(z1b,(i-1)>>1, j>>1) + vf<48>(z1b,(i+1)>>1, j>>1));
          else if (!ie && je)  add = 0.5f*(vf<48>(z1b, i>>1, (j-1)>>1) + vf<48>(z1b, i>>1, (j+1)>>1));
          else                 add = 0.5f*(vf<48>(z1b,(i+1)>>1,(j-1)>>1) + vf<48>(z1b,(i-1)>>1,(j+1)>>1));
          z0[di][dj] += add;
        }
        bufA[j*NXN + i] = z0[di][dj];
      }
    __syncthreads();
    // T2: Az0 via gather; c = omega*D^-1*(r - Az0); publish c to bufB
    float az[3][3], c[3][3];
    {
      float Wm[5][5];
      GATHER5x5(Wm, z0, bufA);
      #pragma unroll
      for (int di = 0; di < 3; di++)
        #pragma unroll
        for (int dj = 0; dj < 3; dj++){
          float av; STENCIL(Wm, di, dj, av);
          az[di][dj] = av;
          float cv = OMEGA * invd[di][dj] * (r[di][dj] - av);
          c[di][dj] = cv;
          bufB[(j0+dj)*NXN + (i0+di)] = cv;
        }
    }
    __syncthreads();
    // T3: Ac via gather; w = Az0 + Ac; znew = z0 + c; dots
    double gp = 0.0, dp = 0.0;
    {
      float Wm[5][5];
      GATHER5x5(Wm, c, bufB);
      #pragma unroll
      for (int di = 0; di < 3; di++)
        #pragma unroll
        for (int dj = 0; dj < 3; dj++){
          float av; STENCIL(Wm, di, dj, av);
          float wv = az[di][dj] + av;
          w[di][dj] = wv;
          float zn = z0[di][dj] + c[di][dj];
          z0[di][dj] = zn;
          gp += (double)r[di][dj] * (double)zn;
          dp += (double)wv        * (double)zn;
        }
    }
    dual_warp_red(gp, dp);
    if (lane == 0){ pA[wid] = gp; pB[wid] = dp; }
    __syncthreads();
    double gamma = sum16_tree(pA);
    double delta = sum16_tree(pB);
    if (it == 0) gamma0 = gamma;
    if (gamma <= gamma0 * 1e-9 || !(delta > 0.0)) break;   // safety floor

    double beta  = (it == 0) ? 0.0 : gamma / gamma_old;
    double alpha = (it == 0) ? gamma / delta
                             : gamma / (delta - beta * gamma / alpha_old);
    gamma_old = gamma; alpha_old = alpha;
    float bf = (float)beta, af = (float)alpha;

    #pragma unroll
    for (int di = 0; di < 3; di++)
      #pragma unroll
      for (int dj = 0; dj < 3; dj++){
        float pn = z0[di][dj] + bf * p[di][dj];  p[di][dj] = pn;
        float sn = w[di][dj]  + bf * s[di][dj];  s[di][dj] = sn;
        x[di][dj] += af * pn;
        r[di][dj] -= af * sn;
      }

    if (alpha * gamma <= ATOL_E) break;   // energy-error tail bound
  }

  __syncthreads();
  // ---- final u = u0lin + x into bufA ----
  #pragma unroll
  for (int di = 0; di < 3; di++)
    #pragma unroll
    for (int dj = 0; dj < 3; dj++){
      int i = i0+di, j = j0+dj;
      float u;
      if (i == 0) u = 1.f;
      else if (i == NXN-1) u = 0.f;
      else u = 1.f - (float)i*(1.f/95.f) + x[di][dj];
      bufA[j*NXN + i] = u;
    }
  __syncthreads();

  // ---- energy ----
  float U[4][4];
  #pragma unroll
  for (int a = 0; a < 4; a++)
    #pragma unroll
    for (int b = 0; b < 4; b++){
      int gi = i0+a, gj = j0+b;
      U[a][b] = (gi < NXN && gj < NXN) ? bufA[gj*NXN + gi] : 0.f;
    }
  double ep = 0.0;
  #pragma unroll
  for (int di = 0; di < 3; di++)
    #pragma unroll
    for (int dj = 0; dj < 3; dj++){
      int ci = i0+di, cj = j0+dj;
      if (ci < NCW && cj < NCW){
        float sig = S[di+1][dj+1];
        float u00 = U[di][dj], uE = U[di+1][dj], uN = U[di][dj+1], uNE = U[di+1][dj+1];
        float gxA = uE - u00, gyA = uN - u00;
        float gxB = -2.f*uE + uNE + uN, gyB = uE - uNE;
        ep += (double)(sig * 0.5f * (gxA*gxA + gyA*gyA + gxB*gxB + gyB*gyB));
      }
    }
  {
    double dummy = 0.0;
    dual_warp_red(ep, dummy);
    if (lane == 0) pA[wid] = ep;
  }
  __syncthreads();
  if (tid == 0) out[0] = (float)sum16_tree(pA);
}

extern "C" void kernel_launch(void* const* d_in, const int* in_sizes, int n_in,
                              void* d_out, int out_size, void* d_ws, size_t ws_size,
                              hipStream_t stream){
  (void)d_ws; (void)ws_size; (void)out_size;
  int mi = 0;
  for (int k = 0; k < n_in; k++) if (in_sizes[k] == 9025) { mi = k; break; }
  const float* mask = (const float*)d_in[mi];
  fem_mgcg_kernel<<<dim3(1), dim3(NTHREADS), 0, stream>>>(mask, (float*)d_out);
}

// Round 18
// 286.433 us; speedup vs baseline: 1.4128x; 1.4128x over previous
//
#include <hip/hip_runtime.h>

#define NXN 96
#define NNODE (NXN*NXN)
#define NCW 95
#define NTHREADS 1024
#define NWAVES (NTHREADS/64)
#define MAXIT_OUT 300
#define ATOL_E 4e-3       // absolute tail bound on alpha*gamma (err ~0.8*ATOL raw -> ~1-2 bf16 ulps, budget 6.33e-3)
#define OMEGA 0.6f        // fine-level smoother (lambda_max <= 3)
#define OMEGA_C 0.45f     // Galerkin coarse levels (lambda_max <= 4)

__device__ __forceinline__ void dual_warp_red(double& a, double& b){
  #pragma unroll
  for (int off = 32; off > 0; off >>= 1){
    a += __shfl_down(a, off, 64);
    b += __shfl_down(b, off, 64);
  }
}

__device__ __forceinline__ double sum16_tree(const double* buf){
  double t0 = buf[0]  + buf[1],  t1 = buf[2]  + buf[3];
  double t2 = buf[4]  + buf[5],  t3 = buf[6]  + buf[7];
  double t4 = buf[8]  + buf[9],  t5 = buf[10] + buf[11];
  double t6 = buf[12] + buf[13], t7 = buf[14] + buf[15];
  double u0 = t0 + t1, u1 = t2 + t3, u2 = t4 + t5, u3 = t6 + t7;
  return (u0 + u1) + (u2 + u3);
}

// ---- level helpers ----
template<int N, int NC>
__device__ __forceinline__ float sgf(const float* sig, int ci, int cj){
  return (ci >= 0 && ci < NC && cj >= 0 && cj < NC) ? sig[cj*NC + ci] : 0.f;
}
template<int N>
__device__ __forceinline__ float vf(const float* v, int i, int j){
  return (i >= 0 && i < N && j >= 0 && j < N) ? v[j*N + i] : 0.f;
}
// Galerkin (per-triangle sigma) 7-pt stencil (verified R11: zero row-sum,
// symmetric, reduces to shared-sigma stencil when sA==sB).
template<int N, int NC>
__device__ __forceinline__ float diagG(const float* sA, const float* sB, int i, int j){
  float a = sgf<N,NC>(sA,i,j),   b = sgf<N,NC>(sA,i-1,j), c = sgf<N,NC>(sB,i-1,j);
  float d = sgf<N,NC>(sA,i,j-1), e = sgf<N,NC>(sB,i,j-1), f = sgf<N,NC>(sB,i-1,j-1);
  return a + 0.5f*b + 2.5f*c + 0.5f*d + 0.5f*e + f;
}
template<int N, int NC>
__device__ __forceinline__ float applyG(const float* sA, const float* sB, const float* v, int i, int j){
  float a = sgf<N,NC>(sA,i,j),   b = sgf<N,NC>(sA,i-1,j), c = sgf<N,NC>(sB,i-1,j);
  float d = sgf<N,NC>(sA,i,j-1), e = sgf<N,NC>(sB,i,j-1), f = sgf<N,NC>(sB,i-1,j-1);
  return (a + 0.5f*b + 2.5f*c + 0.5f*d + 0.5f*e + f)*vf<N>(v,i,j)
       + 0.5f*(e - a)*vf<N>(v,i+1,j)
       + 0.5f*(f - b)*vf<N>(v,i-1,j)
       - (0.5f*a + 1.5f*c)*vf<N>(v,i,j+1)
       - (0.5f*d + 1.5f*f)*vf<N>(v,i,j-1)
       - c*vf<N>(v,i-1,j+1)
       - e*vf<N>(v,i+1,j-1);
}
// residual (own level, full parallelism) — kept as its OWN phase (frrs-style
// recompute fusion spills: confirmed R7 + R16, WRITE_SIZE 868->1344 KB)
template<int N, int NC>
__device__ void residual_lvl(const float* sA, const float* sB, const float* f, const float* z,
                             float* dout, int tid){
  for (int n = tid; n < N*N; n += NTHREADS){
    int i = n % N, j = n / N;
    dout[n] = (i == 0) ? 0.f : f[n] - applyG<N,NC>(sA,sB,z,i,j);
  }
}
// fused restrict + smooth-from-zero from a PRECOMPUTED fine residual (light, no spill)
template<int Nf, int Nc>
__device__ void rrs0(const float* dfine, const float* idl, float* fc, float* zc, int tid){
  for (int n = tid; n < Nc*Nc; n += NTHREADS){
    int I = n % Nc, J = n / Nc;
    float v = 0.f;
    if (I != 0){
      int fi = 2*I, fj = 2*J;
      v = vf<Nf>(dfine,fi,fj)
        + 0.5f*( vf<Nf>(dfine,fi+1,fj) + vf<Nf>(dfine,fi-1,fj)
               + vf<Nf>(dfine,fi,fj+1) + vf<Nf>(dfine,fi,fj-1)
               + vf<Nf>(dfine,fi+1,fj-1) + vf<Nf>(dfine,fi-1,fj+1) );
    }
    fc[n] = v;
    zc[n] = v * idl[n];
  }
}
template<int Nf, int Nc>
__device__ void prolong_add(const float* zc, float* zfine, int tid){
  for (int n = tid; n < Nf*Nf; n += NTHREADS){
    int i = n % Nf, j = n / Nf;
    if (i == 0) continue;
    int ie = i & 1, je = j & 1;
    float add;
    if (!ie && !je)      add = vf<Nc>(zc, i>>1, j>>1);
    else if (ie && !je)  add = 0.5f*(vf<Nc>(zc,(i-1)>>1, j>>1) + vf<Nc>(zc,(i+1)>>1, j>>1));
    else if (!ie && je)  add = 0.5f*(vf<Nc>(zc, i>>1, (j-1)>>1) + vf<Nc>(zc, i>>1, (j+1)>>1));
    else                 add = 0.5f*(vf<Nc>(zc,(i+1)>>1,(j-1)>>1) + vf<Nc>(zc,(i-1)>>1,(j+1)>>1));
    zfine[n] += add;
  }
}
// post-smooth, double-buffered; idl = omega/diag (0 on BC rows)
template<int N, int NC>
__device__ void post_smooth_db(const float* sA, const float* sB, const float* idl, const float* f,
                               const float* zin, float* zout, int tid){
  for (int n = tid; n < N*N; n += NTHREADS){
    int i = n % N, j = n / N;
    zout[n] = zin[n] + (f[n] - applyG<N,NC>(sA,sB,zin,i,j)) * idl[n];
  }
}

__global__ __launch_bounds__(NTHREADS, 1)
void fem_mgcg_kernel(const float* __restrict__ mask, float* __restrict__ out){
  __shared__ float bufA[NNODE];
  __shared__ float bufB[NNODE];
  __shared__ float z1[48*48], f1[48*48], z1b[48*48];
  __shared__ float z2[24*24], f2[24*24], z2b[24*24];
  __shared__ float z3[12*12], f3[12*12], z3b[12*12];
  __shared__ float f4[6*6], z4[6*6], r4[6*6], d4a[6*6], d4b[6*6], zc4[6*6];
  __shared__ float sc1A[47*47], sc1B[47*47];
  __shared__ float sc2A[23*23], sc2B[23*23];
  __shared__ float sc3A[11*11], sc3B[11*11];
  __shared__ float sc4A[5*5],   sc4B[5*5];
  __shared__ float id1[48*48], id2[24*24], id3[12*12], id4[6*6];
  __shared__ float dscratch[48*48];
  __shared__ double pA[NWAVES], pB[NWAVES];

  const int tid = threadIdx.x, lane = tid & 63, wid = tid >> 6;
  const int bx = tid & 31, by = tid >> 5;
  const int i0 = 3*bx, j0 = 3*by;

  // ---- setup: fine sigma window in registers ----
  float S[4][4];
  #pragma unroll
  for (int a = 0; a < 4; a++)
    #pragma unroll
    for (int b = 0; b < 4; b++){
      int ci = i0-1+a, cj = j0-1+b;
      float m = 0.f;
      if (ci >= 0 && ci < NCW && cj >= 0 && cj < NCW)
        m = 0.001f + 0.999f * mask[cj*NCW + ci];
      S[a][b] = m;
    }
  float invd[3][3];
  #pragma unroll
  for (int di = 0; di < 3; di++)
    #pragma unroll
    for (int dj = 0; dj < 3; dj++){
      float cD = S[di+1][dj+1] + 3.f*S[di][dj+1] + S[di+1][dj] + S[di][dj];
      bool isbc = (i0+di == 0) || (i0+di == NXN-1);
      invd[di][dj] = isbc ? 0.f : 1.f/cD;
    }

  // ---- setup: Galerkin per-triangle sigma hierarchies ----
  for (int n = tid; n < 47*47; n += NTHREADS){
    int CI = n % 47, CJ = n / 47;
    float s00 = 0.001f + 0.999f * mask[(2*CJ)*NCW + (2*CI)];
    float s10 = 0.001f + 0.999f * mask[(2*CJ)*NCW + (2*CI+1)];
    float s01 = 0.001f + 0.999f * mask[(2*CJ+1)*NCW + (2*CI)];
    float s11 = 0.001f + 0.999f * mask[(2*CJ+1)*NCW + (2*CI+1)];
    sc1A[n] = 0.25f*(2.f*s00 + s10 + s01);
    sc1B[n] = 0.25f*(2.f*s11 + s10 + s01);
  }
  __syncthreads();
  for (int n = tid; n < 23*23; n += NTHREADS){
    int CI = n % 23, CJ = n / 23;
    int b00 = (2*CJ)*47 + 2*CI, b10 = b00+1, b01 = b00+47, b11 = b01+1;
    sc2A[n] = 0.25f*(sc1A[b00] + sc1B[b00] + sc1A[b10] + sc1A[b01]);
    sc2B[n] = 0.25f*(sc1A[b11] + sc1B[b11] + sc1B[b10] + sc1B[b01]);
  }
  for (int n = tid; n < 48*48; n += NTHREADS){
    int i = n % 48, j = n / 48;
    id1[n] = (i == 0) ? 0.f : OMEGA_C / diagG<48,47>(sc1A, sc1B, i, j);
  }
  __syncthreads();
  for (int n = tid; n < 11*11; n += NTHREADS){
    int CI = n % 11, CJ = n / 11;
    int b00 = (2*CJ)*23 + 2*CI, b10 = b00+1, b01 = b00+23, b11 = b01+1;
    sc3A[n] = 0.25f*(sc2A[b00] + sc2B[b00] + sc2A[b10] + sc2A[b01]);
    sc3B[n] = 0.25f*(sc2A[b11] + sc2B[b11] + sc2B[b10] + sc2B[b01]);
  }
  for (int n = tid; n < 24*24; n += NTHREADS){
    int i = n % 24, j = n / 24;
    id2[n] = (i == 0) ? 0.f : OMEGA_C / diagG<24,23>(sc2A, sc2B, i, j);
  }
  __syncthreads();
  for (int n = tid; n < 5*5; n += NTHREADS){
    int CI = n % 5, CJ = n / 5;
    int b00 = (2*CJ)*11 + 2*CI, b10 = b00+1, b01 = b00+11, b11 = b01+1;
    sc4A[n] = 0.25f*(sc3A[b00] + sc3B[b00] + sc3A[b10] + sc3A[b01]);
    sc4B[n] = 0.25f*(sc3A[b11] + sc3B[b11] + sc3B[b10] + sc3B[b01]);
  }
  for (int n = tid; n < 12*12; n += NTHREADS){
    int i = n % 12, j = n / 12;
    id3[n] = (i == 0) ? 0.f : OMEGA_C / diagG<12,11>(sc3A, sc3B, i, j);
  }
  __syncthreads();
  for (int n = tid; n < 36; n += NTHREADS){
    int i = n % 6, j = n / 6;
    id4[n] = (i == 0) ? 0.f : 1.f / diagG<6,5>(sc4A, sc4B, i, j);   // plain 1/diag
  }
  __syncthreads();

  #define STENCIL(Wm, di, dj, dst)                                          \
    {                                                                        \
      int i_ = i0+(di);                                                      \
      bool isbc_ = (i_ == 0) || (i_ == NXN-1);                               \
      float s00 = S[(di)+1][(dj)+1], sW = S[(di)][(dj)+1];                   \
      float sS  = S[(di)+1][(dj)],   sWS = S[(di)][(dj)];                    \
      float v_ = (s00 + 3.f*sW + sS + sWS)*Wm[(di)+1][(dj)+1]                \
               + 0.5f*(sS - s00)*Wm[(di)+2][(dj)+1]                          \
               + 0.5f*(sWS - sW)*Wm[(di)][(dj)+1]                            \
               - 0.5f*(s00 + 3.f*sW)*Wm[(di)+1][(dj)+2]                      \
               - 0.5f*(sS + 3.f*sWS)*Wm[(di)+1][(dj)]                        \
               - sW*Wm[(di)][(dj)+2]                                         \
               - sS*Wm[(di)+2][(dj)];                                        \
      dst = isbc_ ? 0.f : v_;                                                \
    }

  #define GATHER5x5(Wm, own, buf)                                           \
    _Pragma("unroll")                                                        \
    for (int a = 0; a < 5; a++)                                              \
      _Pragma("unroll")                                                      \
      for (int b = 0; b < 5; b++){                                           \
        if (a >= 1 && a <= 3 && b >= 1 && b <= 3){ Wm[a][b] = own[a-1][b-1]; continue; } \
        int gi = i0-1+a, gj = j0-1+b;                                        \
        Wm[a][b] = (gi >= 0 && gi < NXN && gj >= 0 && gj < NXN) ? buf[gj*NXN + gi] : 0.f; \
      }

  // Chebyshev(4) bottom-solve on [0.08, 4.0] (Galerkin Gershgorin: lmax<=4)
  const float CH_TH = (4.0f + 0.08f) * 0.5f;
  const float CH_DE = (4.0f - 0.08f) * 0.5f;
  const float CH_SG = CH_TH / CH_DE;
  const float RHO0 = 1.f/CH_SG;
  const float RHO1 = 1.f/(2.f*CH_SG - RHO0);
  const float RHO2 = 1.f/(2.f*CH_SG - RHO1);
  const float RHO3 = 1.f/(2.f*CH_SG - RHO2);
  const float A1 = RHO1*RHO0, B1 = 2.f*RHO1/CH_DE;
  const float A2 = RHO2*RHO1, B2 = 2.f*RHO2/CH_DE;
  const float A3 = RHO3*RHO2, B3 = 2.f*RHO3/CH_DE;

  // ---- warm start u0lin = 1 - i/95 ; r0 = -(A u0lin) on free rows ----
  float x[3][3], r[3][3], z0[3][3], w[3][3], p[3][3], s[3][3];
  #pragma unroll
  for (int di = 0; di < 3; di++)
    #pragma unroll
    for (int dj = 0; dj < 3; dj++){
      x[di][dj] = 0.f; p[di][dj] = 0.f; s[di][dj] = 0.f;
      int i = i0+di;
      float s00 = S[di+1][dj+1], sW = S[di][dj+1], sS = S[di+1][dj], sWS = S[di][dj];
      float uc = 1.f - (float)i     * (1.f/95.f);
      float uE = 1.f - (float)(i+1) * (1.f/95.f);
      float uW = 1.f - (float)(i-1) * (1.f/95.f);
      float v = (s00 + 3.f*sW + sS + sWS)*uc
              + 0.5f*(sS - s00)*uE + 0.5f*(sWS - sW)*uW
              - 0.5f*(s00 + 3.f*sW)*uc - 0.5f*(sS + 3.f*sWS)*uc
              - sW*uW - sS*uE;
      bool isbc = (i == 0) || (i == NXN-1);
      r[di][dj] = isbc ? 0.f : -v;
    }

  double gamma_old = 1.0, alpha_old = 1.0, gamma0 = 0.0;

  // ======== outer PCG (Chronopoulos-Gear) with Galerkin MG V(1,1) ====
  for (int it = 0; it < MAXIT_OUT; ++it){
    // P0: L0 pre-smooth (from zero) + publish to bufA
    #pragma unroll
    for (int di = 0; di < 3; di++)
      #pragma unroll
      for (int dj = 0; dj < 3; dj++){
        float zv = OMEGA * invd[di][dj] * r[di][dj];
        z0[di][dj] = zv;
        bufA[(j0+dj)*NXN + (i0+di)] = zv;
      }
    __syncthreads();
    // P1: fine residual -> bufB
    {
      float Wm[5][5];
      GATHER5x5(Wm, z0, bufA);
      #pragma unroll
      for (int di = 0; di < 3; di++)
        #pragma unroll
        for (int dj = 0; dj < 3; dj++){
          float av; STENCIL(Wm, di, dj, av);
          int i = i0+di;
          bool isbc = (i == 0) || (i == NXN-1);
          bufB[(j0+dj)*NXN + i] = isbc ? 0.f : (r[di][dj] - av);
        }
    }
    __syncthreads();
    // descent
    rrs0<96,48>(bufB, id1, f1, z1, tid);                          __syncthreads();
    residual_lvl<48,47>(sc1A, sc1B, f1, z1, dscratch, tid);       __syncthreads();
    rrs0<48,24>(dscratch, id2, f2, z2, tid);                      __syncthreads();
    residual_lvl<24,23>(sc2A, sc2B, f2, z2, dscratch, tid);       __syncthreads();
    rrs0<24,12>(dscratch, id3, f3, z3, tid);                      __syncthreads();
    residual_lvl<12,11>(sc3A, sc3B, f3, z3, dscratch, tid);       __syncthreads();
    // bottom: restrict 12->6 + Chebyshev d0
    for (int n = tid; n < 36; n += NTHREADS){
      int I = n % 6, J = n / 6;
      float v = 0.f;
      if (I != 0){
        int fi = 2*I, fj = 2*J;
        v = vf<12>(dscratch,fi,fj)
          + 0.5f*( vf<12>(dscratch,fi+1,fj) + vf<12>(dscratch,fi-1,fj)
                 + vf<12>(dscratch,fi,fj+1) + vf<12>(dscratch,fi,fj-1)
                 + vf<12>(dscratch,fi+1,fj-1) + vf<12>(dscratch,fi-1,fj+1) );
      }
      f4[n] = v;
      float d0 = (1.f/CH_TH) * v * id4[n];
      d4a[n] = d0; z4[n] = d0;
    }
    __syncthreads();
    // cheb k=1
    for (int n = tid; n < 36; n += NTHREADS){
      int I = n % 6, J = n / 6;
      if (I == 0){ r4[n] = 0.f; d4b[n] = 0.f; continue; }
      float rn = f4[n] - applyG<6,5>(sc4A, sc4B, d4a, I, J);
      r4[n] = rn;
      float dn = A1*d4a[n] + B1*(rn * id4[n]);
      d4b[n] = dn; z4[n] += dn;
    }
    __syncthreads();
    // cheb k=2
    for (int n = tid; n < 36; n += NTHREADS){
      int I = n % 6, J = n / 6;
      if (I == 0){ d4a[n] = 0.f; continue; }
      float rn = r4[n] - applyG<6,5>(sc4A, sc4B, d4b, I, J);
      r4[n] = rn;
      float dn = A2*d4b[n] + B2*(rn * id4[n]);
      d4a[n] = dn; z4[n] += dn;
    }
    __syncthreads();
    // cheb k=3 (final) -> zc4
    for (int n = tid; n < 36; n += NTHREADS){
      int I = n % 6, J = n / 6;
      if (I == 0){ zc4[n] = 0.f; continue; }
      float rn = r4[n] - applyG<6,5>(sc4A, sc4B, d4a, I, J);
      float dn = A3*d4a[n] + B3*(rn * id4[n]);
      zc4[n] = z4[n] + dn;
    }
    __syncthreads();
    // ascent
    prolong_add<12,6>(zc4, z3, tid);                                 __syncthreads();
    post_smooth_db<12,11>(sc3A, sc3B, id3, f3, z3, z3b, tid);        __syncthreads();
    prolong_add<24,12>(z3b, z2, tid);                                __syncthreads();
    post_smooth_db<24,23>(sc2A, sc2B, id2, f2, z2, z2b, tid);        __syncthreads();
    prolong_add<48,24>(z2b, z1, tid);                                __syncthreads();
    post_smooth_db<48,47>(sc1A, sc1B, id1, f1, z1, z1b, tid);        __syncthreads();
    // T1: L0 prolong from z1b into z0 regs + publish bufA
    #pragma unroll
    for (int di = 0; di < 3; di++)
      #pragma unroll
      for (int dj = 0; dj < 3; dj++){
        int i = i0+di, j = j0+dj;
        if (i != 0 && i != NXN-1){
          int ie = i & 1, je = j & 1;
          float add;
          if (!ie && !je)      add = vf<48>(z1b, i>>1, j>>1);
          else if (ie && !je)  add = 0.5f*(vf<48>(z1b,(i-1)>>1, j>>1) + vf<48>(z1b,(i+1)>>1, j>>1));
          else if (!ie && je)  add = 0.5f*(vf<48>(z1b, i>>1, (j-1)>>1) + vf<48>(z1b, i>>1, (j+1)>>1));
          else                 add = 0.5f*(vf<48>(z1b,(i+1)>>1,(j-1)>>1) + vf<48>(z1b,(i-1)>>1,(j+1)>>1));
          z0[di][dj] += add;
        }
        bufA[j*NXN + i] = z0[di][dj];
      }
    __syncthreads();
    // T2: Az0 via gather; c = omega*D^-1*(r - Az0); publish c to bufB
    float az[3][3], c[3][3];
    {
      float Wm[5][5];
      GATHER5x5(Wm, z0, bufA);
      #pragma unroll
      for (int di = 0; di < 3; di++)
        #pragma unroll
        for (int dj = 0; dj < 3; dj++){
          float av; STENCIL(Wm, di, dj, av);
          az[di][dj] = av;
          float cv = OMEGA * invd[di][dj] * (r[di][dj] - av);
          c[di][dj] = cv;
          bufB[(j0+dj)*NXN + (i0+di)] = cv;
        }
    }
    __syncthreads();
    // T3: Ac via gather; w = Az0 + Ac; znew = z0 + c; dots
    double gp = 0.0, dp = 0.0;
    {
      float Wm[5][5];
      GATHER5x5(Wm, c, bufB);
      #pragma unroll
      for (int di = 0; di < 3; di++)
        #pragma unroll
        for (int dj = 0; dj < 3; dj++){
          float av; STENCIL(Wm, di, dj, av);
          float wv = az[di][dj] + av;
          w[di][dj] = wv;
          float zn = z0[di][dj] + c[di][dj];
          z0[di][dj] = zn;
          gp += (double)r[di][dj] * (double)zn;
          dp += (double)wv        * (double)zn;
        }
    }
    dual_warp_red(gp, dp);
    if (lane == 0){ pA[wid] = gp; pB[wid] = dp; }
    __syncthreads();
    double gamma = sum16_tree(pA);
    double delta = sum16_tree(pB);
    if (it == 0) gamma0 = gamma;
    if (gamma <= gamma0 * 1e-9 || !(delta > 0.0)) break;   // safety floor

    double beta  = (it == 0) ? 0.0 : gamma / gamma_old;
    double alpha = (it == 0) ? gamma / delta
                             : gamma / (delta - beta * gamma / alpha_old);
    gamma_old = gamma; alpha_old = alpha;
    float bf = (float)beta, af = (float)alpha;

    #pragma unroll
    for (int di = 0; di < 3; di++)
      #pragma unroll
      for (int dj = 0; dj < 3; dj++){
        float pn = z0[di][dj] + bf * p[di][dj];  p[di][dj] = pn;
        float sn = w[di][dj]  + bf * s[di][dj];  s[di][dj] = sn;
        x[di][dj] += af * pn;
        r[di][dj] -= af * sn;
      }

    if (alpha * gamma <= ATOL_E) break;   // energy-error tail bound
  }

  __syncthreads();
  // ---- final u = u0lin + x into bufA ----
  #pragma unroll
  for (int di = 0; di < 3; di++)
    #pragma unroll
    for (int dj = 0; dj < 3; dj++){
      int i = i0+di, j = j0+dj;
      float u;
      if (i == 0) u = 1.f;
      else if (i == NXN-1) u = 0.f;
      else u = 1.f - (float)i*(1.f/95.f) + x[di][dj];
      bufA[j*NXN + i] = u;
    }
  __syncthreads();

  // ---- energy ----
  float U[4][4];
  #pragma unroll
  for (int a = 0; a < 4; a++)
    #pragma unroll
    for (int b = 0; b < 4; b++){
      int gi = i0+a, gj = j0+b;
      U[a][b] = (gi < NXN && gj < NXN) ? bufA[gj*NXN + gi] : 0.f;
    }
  double ep = 0.0;
  #pragma unroll
  for (int di = 0; di < 3; di++)
    #pragma unroll
    for (int dj = 0; dj < 3; dj++){
      int ci = i0+di, cj = j0+dj;
      if (ci < NCW && cj < NCW){
        float sig = S[di+1][dj+1];
        float u00 = U[di][dj], uE = U[di+1][dj], uN = U[di][dj+1], uNE = U[di+1][dj+1];
        float gxA = uE - u00, gyA = uN - u00;
        float gxB = -2.f*uE + uNE + uN, gyB = uE - uNE;
        ep += (double)(sig * 0.5f * (gxA*gxA + gyA*gyA + gxB*gxB + gyB*gyB));
      }
    }
  {
    double dummy = 0.0;
    dual_warp_red(ep, dummy);
    if (lane == 0) pA[wid] = ep;
  }
  __syncthreads();
  if (tid == 0) out[0] = (float)sum16_tree(pA);
}

extern "C" void kernel_launch(void* const* d_in, const int* in_sizes, int n_in,
                              void* d_out, int out_size, void* d_ws, size_t ws_size,
                              hipStream_t stream){
  (void)d_ws; (void)ws_size; (void)out_size;
  int mi = 0;
  for (int k = 0; k < n_in; k++) if (in_sizes[k] == 9025) { mi = k; break; }
  const float* mask = (const float*)d_in[mi];
  fem_mgcg_kernel<<<dim3(1), dim3(NTHREADS), 0, stream>>>(mask, (float*)d_out);
}

// Round 19
// 285.280 us; speedup vs baseline: 1.4185x; 1.0040x over previous
//
#include <hip/hip_runtime.h>

#define NXN 96
#define NNODE (NXN*NXN)
#define NCW 95
#define NTHREADS 1024
#define NWAVES (NTHREADS/64)
#define MAXIT_OUT 300
#define ATOL_E 4e-3       // absolute tail bound on alpha*gamma (measured: err = 1 bf16 ulp)
#define OMEGA 0.6f        // fine-level smoother (lambda_max <= 3)
#define OMEGA_C 0.45f     // Galerkin coarse levels (lambda_max <= 4)

__device__ __forceinline__ void dual_warp_red(double& a, double& b){
  #pragma unroll
  for (int off = 32; off > 0; off >>= 1){
    a += __shfl_down(a, off, 64);
    b += __shfl_down(b, off, 64);
  }
}

__device__ __forceinline__ double sum16_tree(const double* buf){
  double t0 = buf[0]  + buf[1],  t1 = buf[2]  + buf[3];
  double t2 = buf[4]  + buf[5],  t3 = buf[6]  + buf[7];
  double t4 = buf[8]  + buf[9],  t5 = buf[10] + buf[11];
  double t6 = buf[12] + buf[13], t7 = buf[14] + buf[15];
  double u0 = t0 + t1, u1 = t2 + t3, u2 = t4 + t5, u3 = t6 + t7;
  return (u0 + u1) + (u2 + u3);
}

// ---- level helpers ----
template<int N, int NC>
__device__ __forceinline__ float sgf(const float* sig, int ci, int cj){
  return (ci >= 0 && ci < NC && cj >= 0 && cj < NC) ? sig[cj*NC + ci] : 0.f;
}
template<int N>
__device__ __forceinline__ float vf(const float* v, int i, int j){
  return (i >= 0 && i < N && j >= 0 && j < N) ? v[j*N + i] : 0.f;
}
// Galerkin (per-triangle sigma) 7-pt stencil (verified R11).
template<int N, int NC>
__device__ __forceinline__ float diagG(const float* sA, const float* sB, int i, int j){
  float a = sgf<N,NC>(sA,i,j),   b = sgf<N,NC>(sA,i-1,j), c = sgf<N,NC>(sB,i-1,j);
  float d = sgf<N,NC>(sA,i,j-1), e = sgf<N,NC>(sB,i,j-1), f = sgf<N,NC>(sB,i-1,j-1);
  return a + 0.5f*b + 2.5f*c + 0.5f*d + 0.5f*e + f;
}
template<int N, int NC>
__device__ __forceinline__ float applyG(const float* sA, const float* sB, const float* v, int i, int j){
  float a = sgf<N,NC>(sA,i,j),   b = sgf<N,NC>(sA,i-1,j), c = sgf<N,NC>(sB,i-1,j);
  float d = sgf<N,NC>(sA,i,j-1), e = sgf<N,NC>(sB,i,j-1), f = sgf<N,NC>(sB,i-1,j-1);
  return (a + 0.5f*b + 2.5f*c + 0.5f*d + 0.5f*e + f)*vf<N>(v,i,j)
       + 0.5f*(e - a)*vf<N>(v,i+1,j)
       + 0.5f*(f - b)*vf<N>(v,i-1,j)
       - (0.5f*a + 1.5f*c)*vf<N>(v,i,j+1)
       - (0.5f*d + 1.5f*f)*vf<N>(v,i,j-1)
       - c*vf<N>(v,i-1,j+1)
       - e*vf<N>(v,i+1,j-1);
}
// residual (own level, full parallelism) — own phase (fusion spills: R7+R16)
template<int N, int NC>
__device__ void residual_lvl(const float* sA, const float* sB, const float* f, const float* z,
                             float* dout, int tid){
  for (int n = tid; n < N*N; n += NTHREADS){
    int i = n % N, j = n / N;
    dout[n] = (i == 0) ? 0.f : f[n] - applyG<N,NC>(sA,sB,z,i,j);
  }
}
// fused restrict + smooth-from-zero from a PRECOMPUTED fine residual (light, no spill)
template<int Nf, int Nc>
__device__ void rrs0(const float* dfine, const float* idl, float* fc, float* zc, int tid){
  for (int n = tid; n < Nc*Nc; n += NTHREADS){
    int I = n % Nc, J = n / Nc;
    float v = 0.f;
    if (I != 0){
      int fi = 2*I, fj = 2*J;
      v = vf<Nf>(dfine,fi,fj)
        + 0.5f*( vf<Nf>(dfine,fi+1,fj) + vf<Nf>(dfine,fi-1,fj)
               + vf<Nf>(dfine,fi,fj+1) + vf<Nf>(dfine,fi,fj-1)
               + vf<Nf>(dfine,fi+1,fj-1) + vf<Nf>(dfine,fi-1,fj+1) );
    }
    fc[n] = v;
    zc[n] = v * idl[n];
  }
}
template<int Nf, int Nc>
__device__ void prolong_add(const float* zc, float* zfine, int tid){
  for (int n = tid; n < Nf*Nf; n += NTHREADS){
    int i = n % Nf, j = n / Nf;
    if (i == 0) continue;
    int ie = i & 1, je = j & 1;
    float add;
    if (!ie && !je)      add = vf<Nc>(zc, i>>1, j>>1);
    else if (ie && !je)  add = 0.5f*(vf<Nc>(zc,(i-1)>>1, j>>1) + vf<Nc>(zc,(i+1)>>1, j>>1));
    else if (!ie && je)  add = 0.5f*(vf<Nc>(zc, i>>1, (j-1)>>1) + vf<Nc>(zc, i>>1, (j+1)>>1));
    else                 add = 0.5f*(vf<Nc>(zc,(i+1)>>1,(j-1)>>1) + vf<Nc>(zc,(i-1)>>1,(j+1)>>1));
    zfine[n] += add;
  }
}
// post-smooth, double-buffered; idl = omega/diag (0 on BC rows)
template<int N, int NC>
__device__ void post_smooth_db(const float* sA, const float* sB, const float* idl, const float* f,
                               const float* zin, float* zout, int tid){
  for (int n = tid; n < N*N; n += NTHREADS){
    int i = n % N, j = n / N;
    zout[n] = zin[n] + (f[n] - applyG<N,NC>(sA,sB,zin,i,j)) * idl[n];
  }
}

__global__ __launch_bounds__(NTHREADS, 1)
void fem_mgcg_kernel(const float* __restrict__ mask, float* __restrict__ out){
  __shared__ float bufA[NNODE];
  __shared__ float bufB[NNODE];
  __shared__ float z1[48*48], f1[48*48], z1b[48*48];
  __shared__ float z2[24*24], f2[24*24], z2b[24*24];
  __shared__ float z3[12*12], f3[12*12], z3b[12*12];
  __shared__ float f4[6*6], z4[6*6], r4[6*6], d4a[6*6], d4b[6*6], zc4[6*6];
  __shared__ float sc1A[47*47], sc1B[47*47];
  __shared__ float sc2A[23*23], sc2B[23*23];
  __shared__ float sc3A[11*11], sc3B[11*11];
  __shared__ float sc4A[5*5],   sc4B[5*5];
  __shared__ float id1[48*48], id2[24*24], id3[12*12], id4[6*6];
  __shared__ float dscratch[48*48];
  __shared__ double pA[NWAVES], pB[NWAVES];

  const int tid = threadIdx.x, lane = tid & 63, wid = tid >> 6;
  const int bx = tid & 31, by = tid >> 5;
  const int i0 = 3*bx, j0 = 3*by;

  // ---- setup: fine sigma window in registers ----
  float S[4][4];
  #pragma unroll
  for (int a = 0; a < 4; a++)
    #pragma unroll
    for (int b = 0; b < 4; b++){
      int ci = i0-1+a, cj = j0-1+b;
      float m = 0.f;
      if (ci >= 0 && ci < NCW && cj >= 0 && cj < NCW)
        m = 0.001f + 0.999f * mask[cj*NCW + ci];
      S[a][b] = m;
    }
  float invd[3][3];
  #pragma unroll
  for (int di = 0; di < 3; di++)
    #pragma unroll
    for (int dj = 0; dj < 3; dj++){
      float cD = S[di+1][dj+1] + 3.f*S[di][dj+1] + S[di+1][dj] + S[di][dj];
      bool isbc = (i0+di == 0) || (i0+di == NXN-1);
      invd[di][dj] = isbc ? 0.f : 1.f/cD;
    }

  // ---- setup: Galerkin per-triangle sigma hierarchies ----
  for (int n = tid; n < 47*47; n += NTHREADS){
    int CI = n % 47, CJ = n / 47;
    float s00 = 0.001f + 0.999f * mask[(2*CJ)*NCW + (2*CI)];
    float s10 = 0.001f + 0.999f * mask[(2*CJ)*NCW + (2*CI+1)];
    float s01 = 0.001f + 0.999f * mask[(2*CJ+1)*NCW + (2*CI)];
    float s11 = 0.001f + 0.999f * mask[(2*CJ+1)*NCW + (2*CI+1)];
    sc1A[n] = 0.25f*(2.f*s00 + s10 + s01);
    sc1B[n] = 0.25f*(2.f*s11 + s10 + s01);
  }
  __syncthreads();
  for (int n = tid; n < 23*23; n += NTHREADS){
    int CI = n % 23, CJ = n / 23;
    int b00 = (2*CJ)*47 + 2*CI, b10 = b00+1, b01 = b00+47, b11 = b01+1;
    sc2A[n] = 0.25f*(sc1A[b00] + sc1B[b00] + sc1A[b10] + sc1A[b01]);
    sc2B[n] = 0.25f*(sc1A[b11] + sc1B[b11] + sc1B[b10] + sc1B[b01]);
  }
  for (int n = tid; n < 48*48; n += NTHREADS){
    int i = n % 48, j = n / 48;
    id1[n] = (i == 0) ? 0.f : OMEGA_C / diagG<48,47>(sc1A, sc1B, i, j);
  }
  __syncthreads();
  for (int n = tid; n < 11*11; n += NTHREADS){
    int CI = n % 11, CJ = n / 11;
    int b00 = (2*CJ)*23 + 2*CI, b10 = b00+1, b01 = b00+23, b11 = b01+1;
    sc3A[n] = 0.25f*(sc2A[b00] + sc2B[b00] + sc2A[b10] + sc2A[b01]);
    sc3B[n] = 0.25f*(sc2A[b11] + sc2B[b11] + sc2B[b10] + sc2B[b01]);
  }
  for (int n = tid; n < 24*24; n += NTHREADS){
    int i = n % 24, j = n / 24;
    id2[n] = (i == 0) ? 0.f : OMEGA_C / diagG<24,23>(sc2A, sc2B, i, j);
  }
  __syncthreads();
  for (int n = tid; n < 5*5; n += NTHREADS){
    int CI = n % 5, CJ = n / 5;
    int b00 = (2*CJ)*11 + 2*CI, b10 = b00+1, b01 = b00+11, b11 = b01+1;
    sc4A[n] = 0.25f*(sc3A[b00] + sc3B[b00] + sc3A[b10] + sc3A[b01]);
    sc4B[n] = 0.25f*(sc3A[b11] + sc3B[b11] + sc3B[b10] + sc3B[b01]);
  }
  for (int n = tid; n < 12*12; n += NTHREADS){
    int i = n % 12, j = n / 12;
    id3[n] = (i == 0) ? 0.f : OMEGA_C / diagG<12,11>(sc3A, sc3B, i, j);
  }
  __syncthreads();
  for (int n = tid; n < 36; n += NTHREADS){
    int i = n % 6, j = n / 6;
    id4[n] = (i == 0) ? 0.f : 1.f / diagG<6,5>(sc4A, sc4B, i, j);
  }
  __syncthreads();

  #define STENCIL(Wm, di, dj, dst)                                          \
    {                                                                        \
      int i_ = i0+(di);                                                      \
      bool isbc_ = (i_ == 0) || (i_ == NXN-1);                               \
      float s00 = S[(di)+1][(dj)+1], sW = S[(di)][(dj)+1];                   \
      float sS  = S[(di)+1][(dj)],   sWS = S[(di)][(dj)];                    \
      float v_ = (s00 + 3.f*sW + sS + sWS)*Wm[(di)+1][(dj)+1]                \
               + 0.5f*(sS - s00)*Wm[(di)+2][(dj)+1]                          \
               + 0.5f*(sWS - sW)*Wm[(di)][(dj)+1]                            \
               - 0.5f*(s00 + 3.f*sW)*Wm[(di)+1][(dj)+2]                      \
               - 0.5f*(sS + 3.f*sWS)*Wm[(di)+1][(dj)]                        \
               - sW*Wm[(di)][(dj)+2]                                         \
               - sS*Wm[(di)+2][(dj)];                                        \
      dst = isbc_ ? 0.f : v_;                                                \
    }

  #define GATHER5x5(Wm, own, buf)                                           \
    _Pragma("unroll")                                                        \
    for (int a = 0; a < 5; a++)                                              \
      _Pragma("unroll")                                                      \
      for (int b = 0; b < 5; b++){                                           \
        if (a >= 1 && a <= 3 && b >= 1 && b <= 3){ Wm[a][b] = own[a-1][b-1]; continue; } \
        int gi = i0-1+a, gj = j0-1+b;                                        \
        Wm[a][b] = (gi >= 0 && gi < NXN && gj >= 0 && gj < NXN) ? buf[gj*NXN + gi] : 0.f; \
      }

  // Chebyshev(4) bottom-solve on [0.08, 4.0]
  const float CH_TH = (4.0f + 0.08f) * 0.5f;
  const float CH_DE = (4.0f - 0.08f) * 0.5f;
  const float CH_SG = CH_TH / CH_DE;
  const float RHO0 = 1.f/CH_SG;
  const float RHO1 = 1.f/(2.f*CH_SG - RHO0);
  const float RHO2 = 1.f/(2.f*CH_SG - RHO1);
  const float RHO3 = 1.f/(2.f*CH_SG - RHO2);
  const float A1 = RHO1*RHO0, B1 = 2.f*RHO1/CH_DE;
  const float A2 = RHO2*RHO1, B2 = 2.f*RHO2/CH_DE;
  const float A3 = RHO3*RHO2, B3 = 2.f*RHO3/CH_DE;

  // ---- warm start u0lin = 1 - i/95 ; r0 = -(A u0lin) on free rows ----
  float x[3][3], r[3][3], z0[3][3], w[3][3], p[3][3], s[3][3];
  #pragma unroll
  for (int di = 0; di < 3; di++)
    #pragma unroll
    for (int dj = 0; dj < 3; dj++){
      x[di][dj] = 0.f; p[di][dj] = 0.f; s[di][dj] = 0.f;
      int i = i0+di;
      float s00 = S[di+1][dj+1], sW = S[di][dj+1], sS = S[di+1][dj], sWS = S[di][dj];
      float uc = 1.f - (float)i     * (1.f/95.f);
      float uE = 1.f - (float)(i+1) * (1.f/95.f);
      float uW = 1.f - (float)(i-1) * (1.f/95.f);
      float v = (s00 + 3.f*sW + sS + sWS)*uc
              + 0.5f*(sS - s00)*uE + 0.5f*(sWS - sW)*uW
              - 0.5f*(s00 + 3.f*sW)*uc - 0.5f*(sS + 3.f*sWS)*uc
              - sW*uW - sS*uE;
      bool isbc = (i == 0) || (i == NXN-1);
      r[di][dj] = isbc ? 0.f : -v;
    }

  double gamma_old = 1.0, alpha_old = 1.0, gamma0 = 0.0;

  // ======== outer PCG (Chronopoulos-Gear) with Galerkin MG V(1,1) ====
  for (int it = 0; it < MAXIT_OUT; ++it){
    // P0: L0 pre-smooth (from zero) + publish to bufA
    #pragma unroll
    for (int di = 0; di < 3; di++)
      #pragma unroll
      for (int dj = 0; dj < 3; dj++){
        float zv = OMEGA * invd[di][dj] * r[di][dj];
        z0[di][dj] = zv;
        bufA[(j0+dj)*NXN + (i0+di)] = zv;
      }
    __syncthreads();
    // P1: fine residual -> bufB
    {
      float Wm[5][5];
      GATHER5x5(Wm, z0, bufA);
      #pragma unroll
      for (int di = 0; di < 3; di++)
        #pragma unroll
        for (int dj = 0; dj < 3; dj++){
          float av; STENCIL(Wm, di, dj, av);
          int i = i0+di;
          bool isbc = (i == 0) || (i == NXN-1);
          bufB[(j0+dj)*NXN + i] = isbc ? 0.f : (r[di][dj] - av);
        }
    }
    __syncthreads();
    // descent
    rrs0<96,48>(bufB, id1, f1, z1, tid);                          __syncthreads();
    residual_lvl<48,47>(sc1A, sc1B, f1, z1, dscratch, tid);       __syncthreads();
    rrs0<48,24>(dscratch, id2, f2, z2, tid);                      __syncthreads();
    residual_lvl<24,23>(sc2A, sc2B, f2, z2, dscratch, tid);       __syncthreads();
    rrs0<24,12>(dscratch, id3, f3, z3, tid);                      __syncthreads();
    residual_lvl<12,11>(sc3A, sc3B, f3, z3, dscratch, tid);       __syncthreads();
    // bottom: SINGLE wave-synchronous phase (wave 0 only, no block barriers
    // between sub-steps; within-wave LDS RAW ordered by compiler lgkmcnt).
    // Identical math + FP order to the proven 4-phase version (R15/R17).
    if (wid == 0){
      // restrict 12->6 + Chebyshev d0
      for (int n = lane; n < 36; n += 64){
        int I = n % 6, J = n / 6;
        float v = 0.f;
        if (I != 0){
          int fi = 2*I, fj = 2*J;
          v = vf<12>(dscratch,fi,fj)
            + 0.5f*( vf<12>(dscratch,fi+1,fj) + vf<12>(dscratch,fi-1,fj)
                   + vf<12>(dscratch,fi,fj+1) + vf<12>(dscratch,fi,fj-1)
                   + vf<12>(dscratch,fi+1,fj-1) + vf<12>(dscratch,fi-1,fj+1) );
        }
        f4[n] = v;
        float d0 = (1.f/CH_TH) * v * id4[n];
        d4a[n] = d0; z4[n] = d0;
      }
      // cheb k=1
      for (int n = lane; n < 36; n += 64){
        int I = n % 6, J = n / 6;
        if (I == 0){ r4[n] = 0.f; d4b[n] = 0.f; continue; }
        float rn = f4[n] - applyG<6,5>(sc4A, sc4B, d4a, I, J);
        r4[n] = rn;
        float dn = A1*d4a[n] + B1*(rn * id4[n]);
        d4b[n] = dn; z4[n] += dn;
      }
      // cheb k=2
      for (int n = lane; n < 36; n += 64){
        int I = n % 6, J = n / 6;
        if (I == 0){ d4a[n] = 0.f; continue; }
        float rn = r4[n] - applyG<6,5>(sc4A, sc4B, d4b, I, J);
        r4[n] = rn;
        float dn = A2*d4b[n] + B2*(rn * id4[n]);
        d4a[n] = dn; z4[n] += dn;
      }
      // cheb k=3 (final) -> zc4
      for (int n = lane; n < 36; n += 64){
        int I = n % 6, J = n / 6;
        if (I == 0){ zc4[n] = 0.f; continue; }
        float rn = r4[n] - applyG<6,5>(sc4A, sc4B, d4a, I, J);
        float dn = A3*d4a[n] + B3*(rn * id4[n]);
        zc4[n] = z4[n] + dn;
      }
    }
    __syncthreads();
    // ascent
    prolong_add<12,6>(zc4, z3, tid);                                 __syncthreads();
    post_smooth_db<12,11>(sc3A, sc3B, id3, f3, z3, z3b, tid);        __syncthreads();
    prolong_add<24,12>(z3b, z2, tid);                                __syncthreads();
    post_smooth_db<24,23>(sc2A, sc2B, id2, f2, z2, z2b, tid);        __syncthreads();
    prolong_add<48,24>(z2b, z1, tid);                                __syncthreads();
    post_smooth_db<48,47>(sc1A, sc1B, id1, f1, z1, z1b, tid);        __syncthreads();
    // T1: L0 prolong from z1b into z0 regs + publish bufA
    #pragma unroll
    for (int di = 0; di < 3; di++)
      #pragma unroll
      for (int dj = 0; dj < 3; dj++){
        int i = i0+di, j = j0+dj;
        if (i != 0 && i != NXN-1){
          int ie = i & 1, je = j & 1;
          float add;
          if (!ie && !je)      add = vf<48>(z1b, i>>1, j>>1);
          else if (ie && !je)  add = 0.5f*(vf<48>(z1b,(i-1)>>1, j>>1) + vf<48>(z1b,(i+1)>>1, j>>1));
          else if (!ie && je)  add = 0.5f*(vf<48>(z1b, i>>1, (j-1)>>1) + vf<48>(z1b, i>>1, (j+1)>>1));
          else                 add = 0.5f*(vf<48>(z1b,(i+1)>>1,(j-1)>>1) + vf<48>(z1b,(i-1)>>1,(j+1)>>1));
          z0[di][dj] += add;
        }
        bufA[j*NXN + i] = z0[di][dj];
      }
    __syncthreads();
    // T2: Az0 via gather; c = omega*D^-1*(r - Az0); publish c to bufB
    float az[3][3], c[3][3];
    {
      float Wm[5][5];
      GATHER5x5(Wm, z0, bufA);
      #pragma unroll
      for (int di = 0; di < 3; di++)
        #pragma unroll
        for (int dj = 0; dj < 3; dj++){
          float av; STENCIL(Wm, di, dj, av);
          az[di][dj] = av;
          float cv = OMEGA * invd[di][dj] * (r[di][dj] - av);
          c[di][dj] = cv;
          bufB[(j0+dj)*NXN + (i0+di)] = cv;
        }
    }
    __syncthreads();
    // T3: Ac via gather; w = Az0 + Ac; znew = z0 + c; dots
    double gp = 0.0, dp = 0.0;
    {
      float Wm[5][5];
      GATHER5x5(Wm, c, bufB);
      #pragma unroll
      for (int di = 0; di < 3; di++)
        #pragma unroll
        for (int dj = 0; dj < 3; dj++){
          float av; STENCIL(Wm, di, dj, av);
          float wv = az[di][dj] + av;
          w[di][dj] = wv;
          float zn = z0[di][dj] + c[di][dj];
          z0[di][dj] = zn;
          gp += (double)r[di][dj] * (double)zn;
          dp += (double)wv        * (double)zn;
        }
    }
    dual_warp_red(gp, dp);
    if (lane == 0){ pA[wid] = gp; pB[wid] = dp; }
    __syncthreads();
    double gamma = sum16_tree(pA);
    double delta = sum16_tree(pB);
    if (it == 0) gamma0 = gamma;
    if (gamma <= gamma0 * 1e-9 || !(delta > 0.0)) break;   // safety floor

    double beta  = (it == 0) ? 0.0 : gamma / gamma_old;
    double alpha = (it == 0) ? gamma / delta
                             : gamma / (delta - beta * gamma / alpha_old);
    gamma_old = gamma; alpha_old = alpha;
    float bf = (float)beta, af = (float)alpha;

    #pragma unroll
    for (int di = 0; di < 3; di++)
      #pragma unroll
      for (int dj = 0; dj < 3; dj++){
        float pn = z0[di][dj] + bf * p[di][dj];  p[di][dj] = pn;
        float sn = w[di][dj]  + bf * s[di][dj];  s[di][dj] = sn;
        x[di][dj] += af * pn;
        r[di][dj] -= af * sn;
      }

    if (alpha * gamma <= ATOL_E) break;   // energy-error tail bound
  }

  __syncthreads();
  // ---- final u = u0lin + x into bufA ----
  #pragma unroll
  for (int di = 0; di < 3; di++)
    #pragma unroll
    for (int dj = 0; dj < 3; dj++){
      int i = i0+di, j = j0+dj;
      float u;
      if (i == 0) u = 1.f;
      else if (i == NXN-1) u = 0.f;
      else u = 1.f - (float)i*(1.f/95.f) + x[di][dj];
      bufA[j*NXN + i] = u;
    }
  __syncthreads();

  // ---- energy ----
  float U[4][4];
  #pragma unroll
  for (int a = 0; a < 4; a++)
    #pragma unroll
    for (int b = 0; b < 4; b++){
      int gi = i0+a, gj = j0+b;
      U[a][b] = (gi < NXN && gj < NXN) ? bufA[gj*NXN + gi] : 0.f;
    }
  double ep = 0.0;
  #pragma unroll
  for (int di = 0; di < 3; di++)
    #pragma unroll
    for (int dj = 0; dj < 3; dj++){
      int ci = i0+di, cj = j0+dj;
      if (ci < NCW && cj < NCW){
        float sig = S[di+1][dj+1];
        float u00 = U[di][dj], uE = U[di+1][dj], uN = U[di][dj+1], uNE = U[di+1][dj+1];
        float gxA = uE - u00, gyA = uN - u00;
        float gxB = -2.f*uE + uNE + uN, gyB = uE - uNE;
        ep += (double)(sig * 0.5f * (gxA*gxA + gyA*gyA + gxB*gxB + gyB*gyB));
      }
    }
  {
    double dummy = 0.0;
    dual_warp_red(ep, dummy);
    if (lane == 0) pA[wid] = ep;
  }
  __syncthreads();
  if (tid == 0) out[0] = (float)sum16_tree(pA);
}

extern "C" void kernel_launch(void* const* d_in, const int* in_sizes, int n_in,
                              void* d_out, int out_size, void* d_ws, size_t ws_size,
                              hipStream_t stream){
  (void)d_ws; (void)ws_size; (void)out_size;
  int mi = 0;
  for (int k = 0; k < n_in; k++) if (in_sizes[k] == 9025) { mi = k; break; }
  const float* mask = (const float*)d_in[mi];
  fem_mgcg_kernel<<<dim3(1), dim3(NTHREADS), 0, stream>>>(mask, (float*)d_out);
}